// Round 5
// baseline (649.885 us; speedup 1.0000x reference)
//
#include <hip/hip_runtime.h>
#include <hip/hip_bf16.h>
#include <hip/hip_fp16.h>

// Problem constants (reference: OUT=11008, IN=4096, B=2, S=2048)
#define K_DIM 4096
#define N_DIM 11008
#define M_DIM 4096  // B*S

typedef _Float16 f16x8 __attribute__((ext_vector_type(8)));
typedef float f32x4 __attribute__((ext_vector_type(4)));

typedef const __attribute__((address_space(1))) void* gas_cptr;
typedef __attribute__((address_space(3))) void* las_ptr;

__device__ __forceinline__ void gload_lds16(const void* g, void* l) {
  // async global->LDS, 16B per lane; LDS dest = wave-uniform base + lane*16
  __builtin_amdgcn_global_load_lds((gas_cptr)g, (las_ptr)l, 16, 0, 0);
}

// ---------------------------------------------------------------------------
// Dequant: W_recon[o][i] = sign * scale * (alpha*Xn + (1-alpha)*Xn^p),
//          Xn = mag / divisor.  8 elements per thread, fp16 output [N][K].
// ---------------------------------------------------------------------------
__global__ __launch_bounds__(256) void dequant_kernel(
    const int* __restrict__ mag, const int* __restrict__ sgn,
    const float* __restrict__ scales, const float* __restrict__ alphas,
    const float* __restrict__ powers, const float* __restrict__ divisors,
    _Float16* __restrict__ Wh) {
  const int VPR = K_DIM / 8;  // 512 vec8 per row
  int v = blockIdx.x * 256 + threadIdx.x;  // grid exactly covers N*K/8
  int o = v / VPR;
  int base = o * K_DIM + (v - o * VPR) * 8;

  int4 m0 = *(const int4*)(mag + base);
  int4 m1 = *(const int4*)(mag + base + 4);
  int4 s0 = *(const int4*)(sgn + base);
  int4 s1 = *(const int4*)(sgn + base + 4);

  float sc = scales[o];
  float al = alphas[o];
  float p  = powers[o];
  float idv = 1.0f / divisors[o];

  int mi[8] = {m0.x, m0.y, m0.z, m0.w, m1.x, m1.y, m1.z, m1.w};
  int si[8] = {s0.x, s0.y, s0.z, s0.w, s1.x, s1.y, s1.z, s1.w};

  f16x8 out;
#pragma unroll
  for (int e = 0; e < 8; ++e) {
    float xn = (float)mi[e] * idv;
    float pw = __powf(xn, p);          // xn==0 -> 0 (exp(-inf))
    float cur = al * xn + (1.0f - al) * pw;
    float w = (float)si[e] * (cur * sc);
    out[e] = (_Float16)w;
  }
  *(f16x8*)&Wh[base] = out;
}

// ---------------------------------------------------------------------------
// x (fp32) -> fp16, 8 elements per thread
// ---------------------------------------------------------------------------
__global__ __launch_bounds__(256) void xconv_kernel(const float* __restrict__ x,
                                                    _Float16* __restrict__ xh) {
  int v = blockIdx.x * 256 + threadIdx.x;
  int base = v * 8;
  float4 a = *(const float4*)(x + base);
  float4 b = *(const float4*)(x + base + 4);
  f16x8 o;
  o[0] = (_Float16)a.x; o[1] = (_Float16)a.y;
  o[2] = (_Float16)a.z; o[3] = (_Float16)a.w;
  o[4] = (_Float16)b.x; o[5] = (_Float16)b.y;
  o[6] = (_Float16)b.z; o[7] = (_Float16)b.w;
  *(f16x8*)&xh[base] = o;
}

// ---------------------------------------------------------------------------
// 256x256 8-phase GEMM_BT (T1+T2+T3+T4+T5), BK=64, 512 threads = 8 waves.
// C[m][n] = sum_k A[m][k] * Bt[n][k];  output f32.
// LDS: 2 dbuf x 4 regions (A-kh0, A-kh1, B-kh0, B-kh1), 16KB each = 128 KiB.
// Swizzle (T2): logical colbyte = physical ^ (((row>>1)&3)<<4)  [verified:
// bank-conflicts == 0 in round 4].
// Pipeline (T3+T4): ALL 4 stages of tile t+1 issued in phase 1 of iter t;
// vmcnt(8) @ phase 2 -> A1,B1(t) resident (issued 1 full iter earlier),
// vmcnt(4) @ phase 4 -> A0,B0(t+1) resident (3.5-phase budget). Oldest-first
// completion (m135) makes these exact. Max 12 outstanding.
// ---------------------------------------------------------------------------
#define BM 256
#define BN 256
#define BK 64
#define NT (K_DIM / BK)   // 64 K-tiles
#define NBN (N_DIM / BN)  // 43
#define NBM (M_DIM / BM)  // 16

#define BAR() __builtin_amdgcn_s_barrier()
#define LGKM0()                                          \
  asm volatile("s_waitcnt lgkmcnt(0)" ::: "memory");     \
  __builtin_amdgcn_sched_barrier(0)
#define VMC(N) asm volatile("s_waitcnt vmcnt(" #N ")" ::: "memory")

// stage one k-half region: 2 gloads/thread (j=0: rows 0-127, j=1: rows 128-255)
#define STAGE(buf_, reg_, gbase_)                                        \
  do {                                                                   \
    gload_lds16((gbase_), &lds[buf_][reg_][wave * 512]);                 \
    gload_lds16((gbase_) + 128 * (size_t)K_DIM,                          \
                &lds[buf_][reg_][4096 + wave * 512]);                    \
  } while (0)

#define LOAD_A4(buf_, kh_, qm_)                                          \
  _Pragma("unroll") for (int m = 0; m < 4; ++m)                          \
      af[m] = *(const f16x8*)&lds[buf_][kh_][aoff + ((qm_)*4 + m) * 512];

#define LOAD_B4(buf_, kh_)                                               \
  _Pragma("unroll") for (int n = 0; n < 4; ++n)                          \
      bf[n] = *(const f16x8*)&lds[buf_][2 + (kh_)][boff + n * 512];

#define MFMA_Q(qm_)                                                      \
  do {                                                                   \
    __builtin_amdgcn_s_setprio(1);                                       \
    _Pragma("unroll") for (int m = 0; m < 4; ++m)                        \
        _Pragma("unroll") for (int n = 0; n < 4; ++n)                    \
            acc[(qm_)*4 + m][n] = __builtin_amdgcn_mfma_f32_16x16x32_f16(\
                af[m], bf[n], acc[(qm_)*4 + m][n], 0, 0, 0);             \
    __builtin_amdgcn_s_setprio(0);                                       \
  } while (0)

__global__ __launch_bounds__(512, 2) void gemm_kernel(
    const _Float16* __restrict__ A, const _Float16* __restrict__ Bt,
    float* __restrict__ C) {
  __shared__ _Float16 lds[2][4][8192];  // 128 KiB

  const int tid = threadIdx.x;
  const int lane = tid & 63;
  const int wave = tid >> 6;
  const int wm = wave >> 2;  // 0..1
  const int wn = wave & 3;   // 0..3

  // XCD-aware swizzle (T1), bm-fastest within XCD chunk: 688 = 8 XCDs x 86;
  // 16 | 688 so bm=g&15, bn=g>>4 is bijective. 32 concurrent blocks/XCD then
  // share ~2 B-panels (4MB -> fits per-XCD L2) instead of 32 distinct ones.
  const int bid = blockIdx.x;
  const int g = (bid & 7) * 86 + (bid >> 3);
  const int bm = g & 15;
  const int bn = g >> 4;
  const size_t row0 = (size_t)bm * BM;
  const size_t col0 = (size_t)bn * BN;

  // ---- staging addressing: region byte P = j*8192 + tid*16 -> row/colbyte
  const int sr = tid >> 2;               // row within j=0 half
  const int pcb = (tid & 3) * 16;        // physical col byte
  const int cb = pcb ^ (((sr >> 1) & 3) << 4);  // logical col byte (T2 swizzle)
  const _Float16* gA = A + (row0 + sr) * (size_t)K_DIM + cb / 2;
  const _Float16* gB = Bt + (col0 + sr) * (size_t)K_DIM + cb / 2;

  // ---- fragment read addressing (f16 offsets within a 8192-f16 region)
  // read row = base16 + (lane&15) -> (row>>1)&3 == (lane>>1)&3
  const int frow = lane & 15;
  const int fpcb = 16 * ((lane >> 4) ^ ((lane >> 1) & 3));  // swizzled col byte
  const int aoff = (wm * 128 + frow) * 32 + fpcb / 2;  // + (frag)*512
  const int boff = (wn * 64 + frow) * 32 + fpcb / 2;   // + n*512

  f32x4 acc[8][4];
#pragma unroll
  for (int m = 0; m < 8; ++m)
#pragma unroll
    for (int n = 0; n < 4; ++n) acc[m][n] = (f32x4)0.0f;

  // ---- prologue: stage all 4 halves of tile 0 into buf 0
  STAGE(0, 0, gA);        // A kh0
  STAGE(0, 2, gB);        // B kh0
  STAGE(0, 1, gA + 32);   // A kh1
  STAGE(0, 3, gB + 32);   // B kh1
  VMC(4);                 // A kh0 + B kh0 resident
  BAR();

  f16x8 af[4], bf[4];

  for (int t = 0; t < NT - 1; ++t) {
    const int cur = t & 1;
    const int nxt = cur ^ 1;
    const _Float16* gAn = gA + (size_t)(t + 1) * BK;
    const _Float16* gBn = gB + (size_t)(t + 1) * BK;

    // Phase 1: kh0, m-half0 | batch-issue ALL stages for tile t+1
    LOAD_A4(cur, 0, 0);
    LOAD_B4(cur, 0);
    STAGE(nxt, 0, gAn);
    STAGE(nxt, 2, gBn);
    STAGE(nxt, 1, gAn + 32);
    STAGE(nxt, 3, gBn + 32);
    BAR(); LGKM0();
    MFMA_Q(0);
    BAR();
    // Phase 2: kh0, m-half1 | vmcnt(8): A1,B1(t) resident (oldest 4 of <=12)
    LOAD_A4(cur, 0, 1);
    VMC(8);
    BAR(); LGKM0();
    MFMA_Q(1);
    BAR();
    // Phase 3: kh1, m-half0
    LOAD_A4(cur, 1, 0);
    LOAD_B4(cur, 1);
    BAR(); LGKM0();
    MFMA_Q(0);
    BAR();
    // Phase 4: kh1, m-half1 | vmcnt(4): A0,B0(t+1) resident
    LOAD_A4(cur, 1, 1);
    VMC(4);
    BAR(); LGKM0();
    MFMA_Q(1);
    BAR();
  }

  // ---- tail: tile NT-1 in buf 1, no staging
  LOAD_A4(1, 0, 0);
  LOAD_B4(1, 0);
  BAR(); LGKM0();
  MFMA_Q(0);
  BAR();
  LOAD_A4(1, 0, 1);
  VMC(0);  // A-kh1, B-kh1 of last tile fully resident
  BAR(); LGKM0();
  MFMA_Q(1);
  BAR();
  LOAD_A4(1, 1, 0);
  LOAD_B4(1, 1);
  BAR(); LGKM0();
  MFMA_Q(0);
  BAR();
  LOAD_A4(1, 1, 1);
  LGKM0();
  MFMA_Q(1);

  // ---- epilogue: C/D layout col=lane&15, row=(lane>>4)*4+r
  const int crow = (lane >> 4) * 4;
  const int ccol = lane & 15;
  float* Cw = C + (row0 + wm * 128 + crow) * (size_t)N_DIM + col0 + wn * 64 + ccol;
#pragma unroll
  for (int m = 0; m < 8; ++m)
#pragma unroll
    for (int n = 0; n < 4; ++n)
#pragma unroll
      for (int r = 0; r < 4; ++r)
        Cw[(size_t)(m * 16 + r) * N_DIM + n * 16] = acc[m][n][r];
}

// ---------------------------------------------------------------------------
extern "C" void kernel_launch(void* const* d_in, const int* in_sizes, int n_in,
                              void* d_out, int out_size, void* d_ws, size_t ws_size,
                              hipStream_t stream) {
  const float* x = (const float*)d_in[0];
  const int* Wmag = (const int*)d_in[1];
  const int* Wsgn = (const int*)d_in[2];
  const float* scales = (const float*)d_in[3];
  const float* alphas = (const float*)d_in[4];
  const float* powers = (const float*)d_in[5];
  const float* divisors = (const float*)d_in[6];
  float* out = (float*)d_out;

  _Float16* xh = (_Float16*)d_ws;                        // 32 MB
  _Float16* Wh = xh + (size_t)M_DIM * K_DIM;             // 90 MB

  // 1) dequantize W -> fp16 [N][K]
  {
    int nthreads_total = (N_DIM * K_DIM) / 8;  // 5,636,096
    dequant_kernel<<<nthreads_total / 256, 256, 0, stream>>>(
        Wmag, Wsgn, scales, alphas, powers, divisors, Wh);
  }
  // 2) x -> fp16 [M][K]
  {
    int nthreads_total = (M_DIM * K_DIM) / 8;  // 2,097,152
    xconv_kernel<<<nthreads_total / 256, 256, 0, stream>>>(x, xh);
  }
  // 3) GEMM: [M][K] x [N][K]^T -> [M][N] f32
  {
    dim3 grid(NBM * NBN);  // 16*43 = 688
    gemm_kernel<<<grid, 512, 0, stream>>>(xh, Wh, out);
  }
}

// Round 6
// 585.311 us; speedup vs baseline: 1.1103x; 1.1103x over previous
//
#include <hip/hip_runtime.h>
#include <hip/hip_bf16.h>
#include <hip/hip_fp16.h>

// Problem constants (reference: OUT=11008, IN=4096, B=2, S=2048)
#define K_DIM 4096
#define N_DIM 11008
#define M_DIM 4096  // B*S

typedef _Float16 f16x8 __attribute__((ext_vector_type(8)));
typedef float f32x4 __attribute__((ext_vector_type(4)));

typedef const __attribute__((address_space(1))) void* gas_cptr;
typedef __attribute__((address_space(3))) void* las_ptr;

__device__ __forceinline__ void gload_lds16(const void* g, void* l) {
  // async global->LDS, 16B per lane; LDS dest = wave-uniform base + lane*16
  __builtin_amdgcn_global_load_lds((gas_cptr)g, (las_ptr)l, 16, 0, 0);
}

// ---------------------------------------------------------------------------
// Dequant: W_recon[o][i] = sign * scale * (alpha*Xn + (1-alpha)*Xn^p),
//          Xn = mag / divisor.  8 elements per thread, fp16 output [N][K].
// ---------------------------------------------------------------------------
__global__ __launch_bounds__(256) void dequant_kernel(
    const int* __restrict__ mag, const int* __restrict__ sgn,
    const float* __restrict__ scales, const float* __restrict__ alphas,
    const float* __restrict__ powers, const float* __restrict__ divisors,
    _Float16* __restrict__ Wh) {
  const int VPR = K_DIM / 8;  // 512 vec8 per row
  int v = blockIdx.x * 256 + threadIdx.x;  // grid exactly covers N*K/8
  int o = v / VPR;
  int base = o * K_DIM + (v - o * VPR) * 8;

  int4 m0 = *(const int4*)(mag + base);
  int4 m1 = *(const int4*)(mag + base + 4);
  int4 s0 = *(const int4*)(sgn + base);
  int4 s1 = *(const int4*)(sgn + base + 4);

  float sc = scales[o];
  float al = alphas[o];
  float p  = powers[o];
  float idv = 1.0f / divisors[o];

  int mi[8] = {m0.x, m0.y, m0.z, m0.w, m1.x, m1.y, m1.z, m1.w};
  int si[8] = {s0.x, s0.y, s0.z, s0.w, s1.x, s1.y, s1.z, s1.w};

  f16x8 out;
#pragma unroll
  for (int e = 0; e < 8; ++e) {
    float xn = (float)mi[e] * idv;
    float pw = __powf(xn, p);          // xn==0 -> 0 (exp(-inf))
    float cur = al * xn + (1.0f - al) * pw;
    float w = (float)si[e] * (cur * sc);
    out[e] = (_Float16)w;
  }
  *(f16x8*)&Wh[base] = out;
}

// ---------------------------------------------------------------------------
// x (fp32) -> fp16, 8 elements per thread
// ---------------------------------------------------------------------------
__global__ __launch_bounds__(256) void xconv_kernel(const float* __restrict__ x,
                                                    _Float16* __restrict__ xh) {
  int v = blockIdx.x * 256 + threadIdx.x;
  int base = v * 8;
  float4 a = *(const float4*)(x + base);
  float4 b = *(const float4*)(x + base + 4);
  f16x8 o;
  o[0] = (_Float16)a.x; o[1] = (_Float16)a.y;
  o[2] = (_Float16)a.z; o[3] = (_Float16)a.w;
  o[4] = (_Float16)b.x; o[5] = (_Float16)b.y;
  o[6] = (_Float16)b.z; o[7] = (_Float16)b.w;
  *(f16x8*)&xh[base] = o;
}

// ---------------------------------------------------------------------------
// 256x256 GEMM_BT, BK=32, depth-3 prefetch, 4 LDS buffers, 512 thr = 8 waves.
// C[m][n] = sum_k A[m][k] * Bt[n][k];  output f32.
// LDS: 4 buffers x {A,B} x 16KB = 128 KiB.  Tile = 2 phases (m-halves),
// 16 MFMA each; B-frags loaded once per tile.  Stages: 2 gloads/phase
// (A of t+3 in ph1, B of t+3 in ph2) -> uniform issue, 12 max outstanding.
// One VMC(8) per tile after ph2's MFMA completes tile t+1's 4 loads,
// issued 5-6 phases earlier (covers ~900cy HBM latency; m135 oldest-first).
// WAR safe: buf (t+3)&3's last read finished before iter t-1 ph2's closing
// barrier; its stages issue after it.
// Swizzle (T2, verified 0 conflicts): colbyte ^= ((row>>1)&3)<<4.
// ---------------------------------------------------------------------------
#define BM 256
#define BN 256
#define BK 32
#define NT (K_DIM / BK)   // 128 K-tiles
#define NBN (N_DIM / BN)  // 43
#define NBM (M_DIM / BM)  // 16

#define BAR() __builtin_amdgcn_s_barrier()
#define LGKM0()                                          \
  asm volatile("s_waitcnt lgkmcnt(0)" ::: "memory");     \
  __builtin_amdgcn_sched_barrier(0)
#define VMC(N) asm volatile("s_waitcnt vmcnt(" #N ")" ::: "memory")

// stage one 256x32 operand tile: 2 gloads/thread (rows 0-127, 128-255)
#define STAGE_A(buf_, gp_)                                               \
  do {                                                                   \
    gload_lds16((gp_), &lds[buf_][0][wave * 512]);                       \
    gload_lds16((gp_) + 128 * (size_t)K_DIM,                             \
                &lds[buf_][0][4096 + wave * 512]);                       \
  } while (0)
#define STAGE_B(buf_, gp_)                                               \
  do {                                                                   \
    gload_lds16((gp_), &lds[buf_][1][wave * 512]);                       \
    gload_lds16((gp_) + 128 * (size_t)K_DIM,                             \
                &lds[buf_][1][4096 + wave * 512]);                       \
  } while (0)

#define LOAD_A4(buf_, qm_)                                               \
  _Pragma("unroll") for (int m = 0; m < 4; ++m)                          \
      af[m] = *(const f16x8*)&lds[buf_][0][aoff + ((qm_)*4 + m) * 512];

#define LOAD_B4(buf_)                                                    \
  _Pragma("unroll") for (int n = 0; n < 4; ++n)                          \
      bf[n] = *(const f16x8*)&lds[buf_][1][boff + n * 512];

#define MFMA_Q(qm_)                                                      \
  do {                                                                   \
    __builtin_amdgcn_s_setprio(1);                                       \
    _Pragma("unroll") for (int m = 0; m < 4; ++m)                        \
        _Pragma("unroll") for (int n = 0; n < 4; ++n)                    \
            acc[(qm_)*4 + m][n] = __builtin_amdgcn_mfma_f32_16x16x32_f16(\
                af[m], bf[n], acc[(qm_)*4 + m][n], 0, 0, 0);             \
    __builtin_amdgcn_s_setprio(0);                                       \
  } while (0)

__global__ __launch_bounds__(512, 2) void gemm_kernel(
    const _Float16* __restrict__ A, const _Float16* __restrict__ Bt,
    float* __restrict__ C) {
  __shared__ _Float16 lds[4][2][8192];  // 128 KiB

  const int tid = threadIdx.x;
  const int lane = tid & 63;
  const int wave = tid >> 6;
  const int wm = wave >> 2;  // 0..1
  const int wn = wave & 3;   // 0..3

  // XCD-aware swizzle (T1), bn-fastest (round-4 proven): 688 = 8 XCDs x 86
  const int bid = blockIdx.x;
  const int g = (bid & 7) * 86 + (bid >> 3);
  const int bm = g / NBN;
  const int bn = g - bm * NBN;
  const size_t row0 = (size_t)bm * BM;
  const size_t col0 = (size_t)bn * BN;

  // ---- staging addressing: region f16 offset = wave*512 + lane*8
  const int sr = tid >> 2;               // row 0..127
  const int pcb = (tid & 3) * 16;        // physical col byte
  const int cb = pcb ^ (((sr >> 1) & 3) << 4);  // logical col byte (T2)
  const _Float16* gA = A + (row0 + sr) * (size_t)K_DIM + cb / 2;
  const _Float16* gB = Bt + (col0 + sr) * (size_t)K_DIM + cb / 2;

  // ---- fragment read addressing (f16 offsets in an 8192-f16 region)
  const int frow = lane & 15;
  const int fpcb = 16 * ((lane >> 4) ^ ((lane >> 1) & 3));  // swizzled col byte
  const int aoff = (wm * 128 + frow) * 32 + fpcb / 2;  // + mfrag*512
  const int boff = (wn * 64 + frow) * 32 + fpcb / 2;   // + n*512

  f32x4 acc[8][4];
#pragma unroll
  for (int m = 0; m < 8; ++m)
#pragma unroll
    for (int n = 0; n < 4; ++n) acc[m][n] = (f32x4)0.0f;

  // ---- prologue: stage tiles 0,1,2
  STAGE_A(0, gA);       STAGE_B(0, gB);
  STAGE_A(1, gA + 32);  STAGE_B(1, gB + 32);
  STAGE_A(2, gA + 64);  STAGE_B(2, gB + 64);
  VMC(8);  // tile 0 resident
  BAR();

  f16x8 af[4], bf[4];

  for (int t = 0; t <= NT - 4; ++t) {
    const int cb_ = t & 3;
    const int nb_ = (t + 3) & 3;
    const _Float16* gAn = gA + (size_t)(t + 3) * BK;
    const _Float16* gBn = gB + (size_t)(t + 3) * BK;

    // Phase 1: m-half0 | stage A(t+3)
    LOAD_A4(cb_, 0);
    LOAD_B4(cb_);
    STAGE_A(nb_, gAn);
    BAR(); LGKM0();
    MFMA_Q(0);
    BAR();
    // Phase 2: m-half1 | stage B(t+3) | VMC(8): tile t+1 resident
    LOAD_A4(cb_, 1);
    STAGE_B(nb_, gBn);
    BAR(); LGKM0();
    MFMA_Q(1);
    VMC(8);
    BAR();
  }

  // ---- tail: tiles NT-3 (buf1), NT-2 (buf2), NT-1 (buf3); no staging
  LOAD_A4(1, 0); LOAD_B4(1);
  BAR(); LGKM0(); MFMA_Q(0); BAR();
  LOAD_A4(1, 1);
  BAR(); LGKM0(); MFMA_Q(1); VMC(4); BAR();

  LOAD_A4(2, 0); LOAD_B4(2);
  BAR(); LGKM0(); MFMA_Q(0); BAR();
  LOAD_A4(2, 1);
  BAR(); LGKM0(); MFMA_Q(1); VMC(0); BAR();

  LOAD_A4(3, 0); LOAD_B4(3);
  BAR(); LGKM0(); MFMA_Q(0); BAR();
  LOAD_A4(3, 1);
  LGKM0(); MFMA_Q(1);

  // ---- epilogue: C/D layout col=lane&15, row=(lane>>4)*4+r
  const int crow = (lane >> 4) * 4;
  const int ccol = lane & 15;
  float* Cw = C + (row0 + wm * 128 + crow) * (size_t)N_DIM + col0 + wn * 64 + ccol;
#pragma unroll
  for (int m = 0; m < 8; ++m)
#pragma unroll
    for (int n = 0; n < 4; ++n)
#pragma unroll
      for (int r = 0; r < 4; ++r)
        Cw[(size_t)(m * 16 + r) * N_DIM + n * 16] = acc[m][n][r];
}

// ---------------------------------------------------------------------------
extern "C" void kernel_launch(void* const* d_in, const int* in_sizes, int n_in,
                              void* d_out, int out_size, void* d_ws, size_t ws_size,
                              hipStream_t stream) {
  const float* x = (const float*)d_in[0];
  const int* Wmag = (const int*)d_in[1];
  const int* Wsgn = (const int*)d_in[2];
  const float* scales = (const float*)d_in[3];
  const float* alphas = (const float*)d_in[4];
  const float* powers = (const float*)d_in[5];
  const float* divisors = (const float*)d_in[6];
  float* out = (float*)d_out;

  _Float16* xh = (_Float16*)d_ws;                        // 32 MB
  _Float16* Wh = xh + (size_t)M_DIM * K_DIM;             // 90 MB

  // 1) dequantize W -> fp16 [N][K]
  {
    int nthreads_total = (N_DIM * K_DIM) / 8;  // 5,636,096
    dequant_kernel<<<nthreads_total / 256, 256, 0, stream>>>(
        Wmag, Wsgn, scales, alphas, powers, divisors, Wh);
  }
  // 2) x -> fp16 [M][K]
  {
    int nthreads_total = (M_DIM * K_DIM) / 8;  // 2,097,152
    xconv_kernel<<<nthreads_total / 256, 256, 0, stream>>>(x, xh);
  }
  // 3) GEMM: [M][K] x [N][K]^T -> [M][N] f32
  {
    dim3 grid(NBM * NBN);  // 16*43 = 688
    gemm_kernel<<<grid, 512, 0, stream>>>(xh, Wh, out);
  }
}